// Round 6
// baseline (126.740 us; speedup 1.0000x reference)
//
#include <hip/hip_runtime.h>
#include <cstdint>
#include <cstddef>

// Problem constants (match reference file)
#define BB 4
#define MM 8192
#define NN 6890
#define NSEG 32
#define SEGN 216          // ceil(6890/32); last segment has 194
#define G 16              // tournament group size
#define GMAX 14           // max groups per segment (216/16 -> 13.5 -> 14)
#define GSTRIDE 17        // group stride in float4 slots (bank-spread pad)
#define CHUNKS 4          // MM / MQ
#define MQ 2048           // queries per nn block (TPB * QT)
#define QT 4              // queries per thread (4 independent scalar chains)
#define TPB 512
#define NQ (BB * MM)      // 32768 queries

static constexpr float MIN_T2 = 0.005f * 0.005f;   // MIN_DIST_THRESH^2

// ws layout (bytes):
//   [0, 8388608)             u64 partials[NSEG][NQ]  (d2_bits<<32 | idx)
//   [8388608, +1024)         float bsum[256]
//   [8389632, +1024)         int   bmatch[256]
#define OFF_BSUM   8388608
#define OFF_BMATCH (8388608 + 1024)

static __device__ __forceinline__ unsigned long long u64min(
    unsigned long long a, unsigned long long b) { return a < b ? a : b; }

// Kernel 1: per-(batch, m-chunk, n-segment) NN, group tournament.
// R5 post-mortem: regression over rounds gives nn = 2.1*(cy/qc) + 22us;
// the 22us fixed term is latency serialization, dominated by the recovery
// rescan (8q x 16 divergent ds_read_b128) executed at VGPR_Count=52 (the
// __launch_bounds__(512) default) -- too few regs to keep 16 reads in
// flight, so read->wait->use serializes ~8 LDS latency rounds per query.
// R6: (a) __launch_bounds__(512,4) -> VGPR ceiling 128 at the same
// 4 waves/SIMD; (b) recovery stages the winning group into c[16] regs
// (64 VGPR) with one waitcnt -> ~1 latency round per query; (c) NSEG=32/
// QT=4 halves recovery reads, partials traffic (16.8->8.4MB), and query
// prologue at identical hot-loop work (864 qc/lane) and identical grid
// shape (512 blocks = 2/CU). Recovery bank windows for 14 groups: dword
// bank = (4g+4t+w)%32; groups g and g+8 share a window -> worst 2-way
// conflict, which is free (m136). Arithmetic, tiebreaks, u64 key identical
// to passing R5 kernel.
__global__ __launch_bounds__(TPB, 4) void nn_kernel(
    const float* __restrict__ cloth, const float* __restrict__ vt,
    const int* __restrict__ valid, unsigned long long* __restrict__ partials)
{
    __shared__ float4 lds[GMAX * GSTRIDE];   // 238 float4 = 3808 B
    int bid   = blockIdx.x;            // 512 blocks = 2/CU
    int seg   = bid & (NSEG - 1);
    int chunk = (bid >> 5) & (CHUNKS - 1);
    int b     = bid >> 7;
    int n0    = seg * SEGN;
    int segn  = (NN - n0 < SEGN) ? (NN - n0) : SEGN;
    int ngroups = (segn + G - 1) / G;
    int npad    = ngroups * G;

    // fused candidate prep: (-2x,-2y,-2z, s2 or +inf if invalid); pads inert
    if (threadIdx.x < npad) {
        float4 v = make_float4(0.0f, 0.0f, 0.0f, __builtin_inff());
        if (threadIdx.x < segn) {
            int n = n0 + threadIdx.x;
            const float* p = vt + ((size_t)b * NN + n) * 3;
            float x = p[0], y = p[1], z = p[2];
            float s2 = x * x + y * y + z * z;
            if (valid[b * NN + n] <= 0) s2 = __builtin_inff();
            v = make_float4(-2.0f * x, -2.0f * y, -2.0f * z, s2);
        }
        int slot = (threadIdx.x >> 4) * GSTRIDE + (threadIdx.x & (G - 1));
        lds[slot] = v;
    }

    float qx[QT], qy[QT], qz[QT], qc2[QT], bd[QT];
    int gb[QT];
    int m0 = chunk * MQ + threadIdx.x;
#pragma unroll
    for (int j = 0; j < QT; j++) {
        int m = m0 + j * TPB;
        const float* p = cloth + ((size_t)b * MM + m) * 3;
        float x = p[0], y = p[1], z = p[2];
        qx[j] = x; qy[j] = y; qz[j] = z;
        qc2[j] = x * x + y * y + z * z;
        bd[j] = __builtin_inff();
        gb[j] = 0;
    }
    __syncthreads();

    // Hot loop: UNFILTERED value-min in shifted space e = s2 - 2 c.s,
    // group tournament, candidates in pairs -> min3 fold.
    for (int g = 0; g < ngroups; g++) {
        int base = g * GSTRIDE;
        float gm[QT];
#pragma unroll
        for (int j = 0; j < QT; j++) gm[j] = __builtin_inff();
#pragma unroll
        for (int t = 0; t < G; t += 2) {
            float4 c0 = lds[base + t];
            float4 c1 = lds[base + t + 1];
#pragma unroll
            for (int j = 0; j < QT; j++) {
                float e0 = fmaf(c0.x, qx[j],
                           fmaf(c0.y, qy[j], fmaf(c0.z, qz[j], c0.w)));
                float e1 = fmaf(c1.x, qx[j],
                           fmaf(c1.y, qy[j], fmaf(c1.z, qz[j], c1.w)));
                gm[j] = fminf(fminf(e0, e1), gm[j]);
            }
        }
#pragma unroll
        for (int j = 0; j < QT; j++) {
            bool ok = gm[j] < bd[j];
            bd[j] = ok ? gm[j] : bd[j];
            gb[j] = ok ? g : gb[j];
        }
    }

    // index recovery: stage the winning group's 16 float4 into registers
    // (all reads in flight, one waitcnt), then pure-VALU equality scan
    // (downward -> lowest index). Same scalar fmaf chain as the scan; min
    // is exact -> e == tgt always found.
    int bi[QT];
#pragma unroll
    for (int j = 0; j < QT; j++) {
        int base = gb[j] * GSTRIDE;
        float4 c[G];
#pragma unroll
        for (int t = 0; t < G; t++) c[t] = lds[base + t];
        float tgt = bd[j];
        int mloc = G;                    // G = not found (unreachable)
#pragma unroll
        for (int t = G - 1; t >= 0; t--) {
            float e = fmaf(c[t].x, qx[j],
                      fmaf(c[t].y, qy[j], fmaf(c[t].z, qz[j], c[t].w)));
            mloc = (e == tgt) ? t : mloc;
        }
        int gi = n0 + (gb[j] << 4) + ((mloc < G) ? mloc : 0);
        bi[j] = (gi > NN - 1) ? (NN - 1) : gi;   // pad corner clamp
    }

    // rare fallback: unfiltered min is a too-close candidate -> rescan this
    // segment with the full filter (if the min passes, all candidates do).
#pragma unroll
    for (int j = 0; j < QT; j++) {
        float tmin = MIN_T2 - qc2[j];
        if (bd[j] < tmin) {
            float fb = __builtin_inff(); int fi = 0;
            for (int i = 0; i < segn; i++) {
                float4 c = lds[(i >> 4) * GSTRIDE + (i & (G - 1))];
                float e = fmaf(c.x, qx[j], fmaf(c.y, qy[j], fmaf(c.z, qz[j], c.w)));
                bool ok = (e >= tmin) && (e < fb);
                fb = ok ? e : fb;
                fi = ok ? (n0 + i) : fi;
            }
            bd[j] = fb; bi[j] = fi;
        }
    }

    // coalesced partial store: d2 = e + qc2 >= MIN_T2 > 0 (or +inf), so
    // float bits order correctly as unsigned; low 32 bits = idx tiebreak.
#pragma unroll
    for (int j = 0; j < QT; j++) {
        int q = b * MM + m0 + j * TPB;
        float d2 = bd[j] + qc2[j];
        unsigned long long key =
            ((unsigned long long)__float_as_uint(d2) << 32) | (unsigned)bi[j];
        partials[(size_t)seg * NQ + q] = key;
    }
}

// Kernel 2: per-query u64-min over NSEG=32 segment partials, fully unrolled
// with 8 independent accumulators so all loads are in flight. Then gather
// target, contribution, block-reduce.
__global__ __launch_bounds__(128) void finalize_kernel(
    const unsigned long long* __restrict__ partials,
    const int* __restrict__ smpl_idx, const float* __restrict__ sdf,
    const int* __restrict__ cloth_idx, const float* __restrict__ sdf_thresh,
    const float* __restrict__ dist_thresh,
    float* __restrict__ bsum, int* __restrict__ bmatch)
{
    int q = blockIdx.x * 128 + threadIdx.x;   // 256 blocks x 128 = NQ
    int b = q >> 13;
    unsigned long long mm[8];
#pragma unroll
    for (int k = 0; k < 8; k++) mm[k] = ~0ULL;
#pragma unroll
    for (int s = 0; s < NSEG; s += 8) {
#pragma unroll
        for (int k = 0; k < 8; k++)
            mm[k] = u64min(mm[k], partials[(size_t)(s + k) * NQ + q]);
    }
    unsigned long long key =
        u64min(u64min(u64min(mm[0], mm[1]), u64min(mm[2], mm[3])),
               u64min(u64min(mm[4], mm[5]), u64min(mm[6], mm[7])));

    float d2  = __uint_as_float((unsigned)(key >> 32));
    int   idx = (int)(unsigned)(key & 0xFFFFFFFFu);
    int target = smpl_idx[b * NN + idx];
    int ci0 = cloth_idx[0], ci1 = cloth_idx[1];
    bool match = (target == ci0) || (target == ci1);
    bool near_ = sqrtf(d2) < dist_thresh[0];     // inf -> false
    float s = sdf[q];
    float contrib = near_ ? (match ? fabsf(s) : fabsf(s - sdf_thresh[0])) : 0.0f;
    int mt = match ? 1 : 0;

    for (int off = 32; off > 0; off >>= 1) {
        contrib += __shfl_down(contrib, off, 64);
        mt      |= __shfl_down(mt, off, 64);
    }
    __shared__ float wsum[2];
    __shared__ int   wmat[2];
    int wave = threadIdx.x >> 6;
    if ((threadIdx.x & 63) == 0) { wsum[wave] = contrib; wmat[wave] = mt; }
    __syncthreads();
    if (threadIdx.x == 0) {
        bsum[blockIdx.x]   = wsum[0] + wsum[1];
        bmatch[blockIdx.x] = wmat[0] | wmat[1];
    }
}

// Kernel 3: 256 block-partials -> 4 batch losses (64 partials per batch,
// one wave per batch).
__global__ __launch_bounds__(256) void reduce_kernel(
    const float* __restrict__ bs, const int* __restrict__ bm,
    float* __restrict__ out)
{
    int t = threadIdx.x;          // batch = t>>6
    float s = bs[t];
    int   m = bm[t];
    for (int off = 32; off > 0; off >>= 1) {
        s += __shfl_down(s, off, 64);
        m |= __shfl_down(m, off, 64);
    }
    if ((t & 63) == 0)
        out[t >> 6] = s * (1.0f / (float)MM) * (m ? 1.0f : 0.0f);
}

extern "C" void kernel_launch(void* const* d_in, const int* in_sizes, int n_in,
                              void* d_out, int out_size, void* d_ws, size_t ws_size,
                              hipStream_t stream)
{
    const float* sdf         = (const float*)d_in[0];
    const float* cloth       = (const float*)d_in[1];
    const int*   smpl_idx    = (const int*)d_in[2];
    const int*   valid       = (const int*)d_in[3];
    const int*   cloth_idx   = (const int*)d_in[4];
    const float* sdf_thresh  = (const float*)d_in[5];
    const float* dist_thresh = (const float*)d_in[6];
    const float* vt          = (const float*)d_in[7];

    char* ws = (char*)d_ws;
    unsigned long long* partials = (unsigned long long*)ws;
    float* bsum   = (float*)(ws + OFF_BSUM);
    int*   bmatch = (int*)(ws + OFF_BMATCH);

    nn_kernel<<<BB * CHUNKS * NSEG, TPB, 0, stream>>>(cloth, vt, valid, partials);
    finalize_kernel<<<NQ / 128, 128, 0, stream>>>(
        partials, smpl_idx, sdf, cloth_idx, sdf_thresh, dist_thresh,
        bsum, bmatch);
    reduce_kernel<<<1, 256, 0, stream>>>(bsum, bmatch, (float*)d_out);
}

// Round 7
// 117.298 us; speedup vs baseline: 1.0805x; 1.0805x over previous
//
#include <hip/hip_runtime.h>
#include <cstdint>
#include <cstddef>

// Problem constants (match reference file)
#define BB 4
#define MM 8192
#define NN 6890
#define NSEG 64
#define SEGN 108          // ceil(6890/64); last segment has 86
#define G 16              // tournament group size
#define GMAX 7            // max groups per segment
#define GSTRIDE 17        // group stride in float4 slots (bank-spread pad)
#define CHUNKS 2          // MM / MQ
#define MQ 4096           // queries per nn block (TPB * QT)
#define QT 8              // queries per thread (8 independent scalar chains)
#define TPB 512
#define NQ (BB * MM)      // 32768 queries
#define NFBLK 256         // finalize blocks

static constexpr float MIN_T2 = 0.005f * 0.005f;   // MIN_DIST_THRESH^2

// ws layout (bytes):
//   [0, 16777216)            u64 partials[NSEG][NQ]  (d2_bits<<32 | idx)
//   [16777216, +48)          accum: float accF[4]; int accM[4]; int counter
#define OFF_ACC 16777216

static __device__ __forceinline__ unsigned long long u64min(
    unsigned long long a, unsigned long long b) { return a < b ? a : b; }

// Kernel 1: per-(batch, m-chunk, n-segment) NN, group tournament.
// == R5 structure (best measured; conflicts ~0, VGPR 52, no spill) ==
// R6 post-mortem: float4 c[16] staging spilled to scratch (FETCH 49MB,
// WRITE 103MB, nn 54us) -- allocator refused 128 VGPR despite bounds.
// R7: batch-4 staging with NAMED float4s only (+16 VGPR, still <=128 ->
// zero occupancy cost at 2 blocks/CU; no array -> no scratch). Recovery:
// 4 rounds of 4 in-flight LDS reads per query instead of ~16 serialized.
// Override order strictly descending t -> tiebreak identical to R5.
// Block 0 also zeroes the finalize accumulators (stream order guarantees
// visibility before finalize starts).
__global__ __launch_bounds__(TPB) void nn_kernel(
    const float* __restrict__ cloth, const float* __restrict__ vt,
    const int* __restrict__ valid, unsigned long long* __restrict__ partials,
    unsigned* __restrict__ acc)
{
    if (blockIdx.x == 0 && threadIdx.x < 12) acc[threadIdx.x] = 0u;

    __shared__ float4 lds[GMAX * GSTRIDE];   // 119 float4 = 1904 B
    int bid   = blockIdx.x;            // 512 blocks = 2/CU
    int seg   = bid & (NSEG - 1);
    int chunk = (bid >> 6) & (CHUNKS - 1);
    int b     = bid >> 7;
    int n0    = seg * SEGN;
    int segn  = (NN - n0 < SEGN) ? (NN - n0) : SEGN;
    int ngroups = (segn + G - 1) / G;
    int npad    = ngroups * G;

    // fused candidate prep: (-2x,-2y,-2z, s2 or +inf if invalid); pads inert
    if (threadIdx.x < npad) {
        float4 v = make_float4(0.0f, 0.0f, 0.0f, __builtin_inff());
        if (threadIdx.x < segn) {
            int n = n0 + threadIdx.x;
            const float* p = vt + ((size_t)b * NN + n) * 3;
            float x = p[0], y = p[1], z = p[2];
            float s2 = x * x + y * y + z * z;
            if (valid[b * NN + n] <= 0) s2 = __builtin_inff();
            v = make_float4(-2.0f * x, -2.0f * y, -2.0f * z, s2);
        }
        int slot = (threadIdx.x >> 4) * GSTRIDE + (threadIdx.x & (G - 1));
        lds[slot] = v;
    }

    float qx[QT], qy[QT], qz[QT], qc2[QT], bd[QT];
    int gb[QT];
    int m0 = chunk * MQ + threadIdx.x;
#pragma unroll
    for (int j = 0; j < QT; j++) {
        int m = m0 + j * TPB;
        const float* p = cloth + ((size_t)b * MM + m) * 3;
        float x = p[0], y = p[1], z = p[2];
        qx[j] = x; qy[j] = y; qz[j] = z;
        qc2[j] = x * x + y * y + z * z;
        bd[j] = __builtin_inff();
        gb[j] = 0;
    }
    __syncthreads();

    // Hot loop: UNFILTERED value-min in shifted space e = s2 - 2 c.s,
    // group tournament, candidates in pairs -> min fold.
    for (int g = 0; g < ngroups; g++) {
        int base = g * GSTRIDE;
        float gm[QT];
#pragma unroll
        for (int j = 0; j < QT; j++) gm[j] = __builtin_inff();
#pragma unroll
        for (int t = 0; t < G; t += 2) {
            float4 c0 = lds[base + t];
            float4 c1 = lds[base + t + 1];
#pragma unroll
            for (int j = 0; j < QT; j++) {
                float e0 = fmaf(c0.x, qx[j],
                           fmaf(c0.y, qy[j], fmaf(c0.z, qz[j], c0.w)));
                float e1 = fmaf(c1.x, qx[j],
                           fmaf(c1.y, qy[j], fmaf(c1.z, qz[j], c1.w)));
                gm[j] = fminf(fminf(e0, e1), gm[j]);
            }
        }
#pragma unroll
        for (int j = 0; j < QT; j++) {
            bool ok = gm[j] < bd[j];
            bd[j] = ok ? gm[j] : bd[j];
            gb[j] = ok ? g : gb[j];
        }
    }

    // index recovery: equality rescan of the winning group, batches of 4
    // candidates staged in NAMED float4s (4 reads in flight, no arrays ->
    // no scratch). Batches processed high->low, within-batch high->low:
    // lowest t evaluated last -> lowest-index override, identical to R5.
    int bi[QT];
#pragma unroll
    for (int j = 0; j < QT; j++) {
        int base = gb[j] * GSTRIDE;
        float tgt = bd[j];
        int mloc = G;                    // G = not found (unreachable)
#pragma unroll
        for (int tb = G - 4; tb >= 0; tb -= 4) {
            float4 ca = lds[base + tb + 3];
            float4 cb = lds[base + tb + 2];
            float4 cc = lds[base + tb + 1];
            float4 cd = lds[base + tb + 0];
            float ea = fmaf(ca.x, qx[j], fmaf(ca.y, qy[j], fmaf(ca.z, qz[j], ca.w)));
            float eb = fmaf(cb.x, qx[j], fmaf(cb.y, qy[j], fmaf(cb.z, qz[j], cb.w)));
            float ec = fmaf(cc.x, qx[j], fmaf(cc.y, qy[j], fmaf(cc.z, qz[j], cc.w)));
            float ed = fmaf(cd.x, qx[j], fmaf(cd.y, qy[j], fmaf(cd.z, qz[j], cd.w)));
            mloc = (ea == tgt) ? (tb + 3) : mloc;
            mloc = (eb == tgt) ? (tb + 2) : mloc;
            mloc = (ec == tgt) ? (tb + 1) : mloc;
            mloc = (ed == tgt) ? (tb + 0) : mloc;
        }
        int gi = n0 + (gb[j] << 4) + ((mloc < G) ? mloc : 0);
        bi[j] = (gi > NN - 1) ? (NN - 1) : gi;   // pad corner clamp
    }

    // rare fallback: unfiltered min is a too-close candidate -> rescan this
    // segment with the full filter (if the min passes, all candidates do).
#pragma unroll
    for (int j = 0; j < QT; j++) {
        float tmin = MIN_T2 - qc2[j];
        if (bd[j] < tmin) {
            float fb = __builtin_inff(); int fi = 0;
            for (int i = 0; i < segn; i++) {
                float4 c = lds[(i >> 4) * GSTRIDE + (i & (G - 1))];
                float e = fmaf(c.x, qx[j], fmaf(c.y, qy[j], fmaf(c.z, qz[j], c.w)));
                bool ok = (e >= tmin) && (e < fb);
                fb = ok ? e : fb;
                fi = ok ? (n0 + i) : fi;
            }
            bd[j] = fb; bi[j] = fi;
        }
    }

    // coalesced partial store: d2 = e + qc2 >= MIN_T2 > 0 (or +inf), so
    // float bits order correctly as unsigned; low 32 bits = idx tiebreak.
#pragma unroll
    for (int j = 0; j < QT; j++) {
        int q = b * MM + m0 + j * TPB;
        float d2 = bd[j] + qc2[j];
        unsigned long long key =
            ((unsigned long long)__float_as_uint(d2) << 32) | (unsigned)bi[j];
        partials[(size_t)seg * NQ + q] = key;
    }
}

// Kernel 2: per-query u64-min over NSEG=64 segment partials (8 independent
// accumulators, all loads in flight), gather target, contribution,
// block-reduce, then device-scope atomic accumulation per batch; the last
// block (counter) computes the 4 final losses. Replaces reduce_kernel
// (saves one launch + gap). acc layout: float accF[4]; int accM[4]; counter.
__global__ __launch_bounds__(128) void finalize_kernel(
    const unsigned long long* __restrict__ partials,
    const int* __restrict__ smpl_idx, const float* __restrict__ sdf,
    const int* __restrict__ cloth_idx, const float* __restrict__ sdf_thresh,
    const float* __restrict__ dist_thresh,
    unsigned* __restrict__ acc, float* __restrict__ out)
{
    int q = blockIdx.x * 128 + threadIdx.x;   // 256 blocks x 128 = NQ
    int b = q >> 13;                          // block lies within one batch
    unsigned long long mm[8];
#pragma unroll
    for (int k = 0; k < 8; k++) mm[k] = ~0ULL;
#pragma unroll
    for (int s = 0; s < NSEG; s += 8) {
#pragma unroll
        for (int k = 0; k < 8; k++)
            mm[k] = u64min(mm[k], partials[(size_t)(s + k) * NQ + q]);
    }
    unsigned long long key =
        u64min(u64min(u64min(mm[0], mm[1]), u64min(mm[2], mm[3])),
               u64min(u64min(mm[4], mm[5]), u64min(mm[6], mm[7])));

    float d2  = __uint_as_float((unsigned)(key >> 32));
    int   idx = (int)(unsigned)(key & 0xFFFFFFFFu);
    int target = smpl_idx[b * NN + idx];
    int ci0 = cloth_idx[0], ci1 = cloth_idx[1];
    bool match = (target == ci0) || (target == ci1);
    bool near_ = sqrtf(d2) < dist_thresh[0];     // inf -> false
    float s = sdf[q];
    float contrib = near_ ? (match ? fabsf(s) : fabsf(s - sdf_thresh[0])) : 0.0f;
    int mt = match ? 1 : 0;

    for (int off = 32; off > 0; off >>= 1) {
        contrib += __shfl_down(contrib, off, 64);
        mt      |= __shfl_down(mt, off, 64);
    }
    __shared__ float wsum[2];
    __shared__ int   wmat[2];
    int wave = threadIdx.x >> 6;
    if ((threadIdx.x & 63) == 0) { wsum[wave] = contrib; wmat[wave] = mt; }
    __syncthreads();

    float* accF = (float*)acc;
    int*   accM = (int*)(acc + 4);
    int*   cnt  = (int*)(acc + 8);
    if (threadIdx.x == 0) {
        atomicAdd(&accF[b], wsum[0] + wsum[1]);      // device-scope (m20)
        atomicOr(&accM[b], wmat[0] | wmat[1]);
        __threadfence();                             // release accum adds
        int old = atomicAdd(cnt, 1);
        if (old == NFBLK - 1) {                      // last block finishes
            __threadfence();                         // acquire
#pragma unroll
            for (int k = 0; k < BB; k++) {
                float sb = atomicAdd(&accF[k], 0.0f);   // coherent RMW read
                int   mb = atomicOr(&accM[k], 0);
                out[k] = sb * (1.0f / (float)MM) * (mb ? 1.0f : 0.0f);
            }
        }
    }
}

extern "C" void kernel_launch(void* const* d_in, const int* in_sizes, int n_in,
                              void* d_out, int out_size, void* d_ws, size_t ws_size,
                              hipStream_t stream)
{
    const float* sdf         = (const float*)d_in[0];
    const float* cloth       = (const float*)d_in[1];
    const int*   smpl_idx    = (const int*)d_in[2];
    const int*   valid       = (const int*)d_in[3];
    const int*   cloth_idx   = (const int*)d_in[4];
    const float* sdf_thresh  = (const float*)d_in[5];
    const float* dist_thresh = (const float*)d_in[6];
    const float* vt          = (const float*)d_in[7];

    char* ws = (char*)d_ws;
    unsigned long long* partials = (unsigned long long*)ws;
    unsigned* acc = (unsigned*)(ws + OFF_ACC);

    nn_kernel<<<BB * CHUNKS * NSEG, TPB, 0, stream>>>(cloth, vt, valid,
                                                      partials, acc);
    finalize_kernel<<<NFBLK, 128, 0, stream>>>(
        partials, smpl_idx, sdf, cloth_idx, sdf_thresh, dist_thresh,
        acc, (float*)d_out);
}

// Round 8
// 108.520 us; speedup vs baseline: 1.1679x; 1.0809x over previous
//
#include <hip/hip_runtime.h>
#include <cstdint>
#include <cstddef>

// Problem constants (match reference file)
#define BB 4
#define MM 8192
#define NN 6890
#define NSEG 64
#define SEGN 108          // ceil(6890/64); last segment has 86
#define G 16              // tournament group size
#define GMAX 7            // max groups per segment
#define GSTRIDE 17        // group stride in float4 slots (bank-spread pad)
#define CHUNKS 2          // MM / MQ
#define MQ 4096           // queries per nn block (TPB * QT)
#define QT 8              // queries per thread (8 independent scalar chains)
#define TPB 512
#define NQ (BB * MM)      // 32768 queries

static constexpr float MIN_T2 = 0.005f * 0.005f;   // MIN_DIST_THRESH^2

// ws layout (bytes):
//   [0, 16777216)            u64 partials[NSEG][NQ]  (d2_bits<<32 | idx)
//   [16777216, +1024)        float bsum[256]
//   [16778240, +1024)        int   bmatch[256]
#define OFF_BSUM   16777216
#define OFF_BMATCH (16777216 + 1024)

static __device__ __forceinline__ unsigned long long u64min(
    unsigned long long a, unsigned long long b) { return a < b ? a : b; }

// Kernel 1: per-(batch, m-chunk, n-segment) NN, group tournament.
// == EXACT R5 structure (best measured: 108.4us total; conflicts ~0,
// no spill, plain partial stores, 3-kernel pipeline) with ONE isolated
// change: batch-4 NAMED-variable recovery staging (R7-validated as
// non-spilling; its gain was masked there by the atomic-fusion regression
// -- 256 blocks RMW-ing one cache line across 8 XCDs serializes at the
// device coherence point, costing more than the saved launch).
// Recovery: 4 rounds of 4 in-flight LDS reads per query instead of ~16
// serialized read->wait->use rounds. Lane-divergent batch reads are
// conflict-free: lanes differ only in g, and GSTRIDE=17 gives disjoint
// dword-bank windows {4g+4t..+3} mod 32 for g=0..6. Tiebreak: batches
// descend, within-batch assignments descend -> lowest matching t assigned
// last == R5's downward scan (verified absmax 0.0 in R7 run).
__global__ __launch_bounds__(TPB) void nn_kernel(
    const float* __restrict__ cloth, const float* __restrict__ vt,
    const int* __restrict__ valid, unsigned long long* __restrict__ partials)
{
    __shared__ float4 lds[GMAX * GSTRIDE];   // 119 float4 = 1904 B
    int bid   = blockIdx.x;            // 512 blocks = 2/CU
    int seg   = bid & (NSEG - 1);
    int chunk = (bid >> 6) & (CHUNKS - 1);
    int b     = bid >> 7;
    int n0    = seg * SEGN;
    int segn  = (NN - n0 < SEGN) ? (NN - n0) : SEGN;
    int ngroups = (segn + G - 1) / G;
    int npad    = ngroups * G;

    // fused candidate prep: (-2x,-2y,-2z, s2 or +inf if invalid); pads inert
    if (threadIdx.x < npad) {
        float4 v = make_float4(0.0f, 0.0f, 0.0f, __builtin_inff());
        if (threadIdx.x < segn) {
            int n = n0 + threadIdx.x;
            const float* p = vt + ((size_t)b * NN + n) * 3;
            float x = p[0], y = p[1], z = p[2];
            float s2 = x * x + y * y + z * z;
            if (valid[b * NN + n] <= 0) s2 = __builtin_inff();
            v = make_float4(-2.0f * x, -2.0f * y, -2.0f * z, s2);
        }
        int slot = (threadIdx.x >> 4) * GSTRIDE + (threadIdx.x & (G - 1));
        lds[slot] = v;
    }

    float qx[QT], qy[QT], qz[QT], qc2[QT], bd[QT];
    int gb[QT];
    int m0 = chunk * MQ + threadIdx.x;
#pragma unroll
    for (int j = 0; j < QT; j++) {
        int m = m0 + j * TPB;
        const float* p = cloth + ((size_t)b * MM + m) * 3;
        float x = p[0], y = p[1], z = p[2];
        qx[j] = x; qy[j] = y; qz[j] = z;
        qc2[j] = x * x + y * y + z * z;
        bd[j] = __builtin_inff();
        gb[j] = 0;
    }
    __syncthreads();

    // Hot loop: UNFILTERED value-min in shifted space e = s2 - 2 c.s,
    // group tournament, candidates in pairs -> min fold.
    for (int g = 0; g < ngroups; g++) {
        int base = g * GSTRIDE;
        float gm[QT];
#pragma unroll
        for (int j = 0; j < QT; j++) gm[j] = __builtin_inff();
#pragma unroll
        for (int t = 0; t < G; t += 2) {
            float4 c0 = lds[base + t];
            float4 c1 = lds[base + t + 1];
#pragma unroll
            for (int j = 0; j < QT; j++) {
                float e0 = fmaf(c0.x, qx[j],
                           fmaf(c0.y, qy[j], fmaf(c0.z, qz[j], c0.w)));
                float e1 = fmaf(c1.x, qx[j],
                           fmaf(c1.y, qy[j], fmaf(c1.z, qz[j], c1.w)));
                gm[j] = fminf(fminf(e0, e1), gm[j]);
            }
        }
#pragma unroll
        for (int j = 0; j < QT; j++) {
            bool ok = gm[j] < bd[j];
            bd[j] = ok ? gm[j] : bd[j];
            gb[j] = ok ? g : gb[j];
        }
    }

    // index recovery: equality rescan of the winning group, batches of 4
    // candidates staged in NAMED float4s (4 reads in flight, no arrays ->
    // no scratch). Batches high->low, within-batch high->low: lowest
    // matching t assigned last -> lowest-index tiebreak, same as R5.
    int bi[QT];
#pragma unroll
    for (int j = 0; j < QT; j++) {
        int base = gb[j] * GSTRIDE;
        float tgt = bd[j];
        int mloc = G;                    // G = not found (unreachable)
#pragma unroll
        for (int tb = G - 4; tb >= 0; tb -= 4) {
            float4 ca = lds[base + tb + 3];
            float4 cb = lds[base + tb + 2];
            float4 cc = lds[base + tb + 1];
            float4 cd = lds[base + tb + 0];
            float ea = fmaf(ca.x, qx[j], fmaf(ca.y, qy[j], fmaf(ca.z, qz[j], ca.w)));
            float eb = fmaf(cb.x, qx[j], fmaf(cb.y, qy[j], fmaf(cb.z, qz[j], cb.w)));
            float ec = fmaf(cc.x, qx[j], fmaf(cc.y, qy[j], fmaf(cc.z, qz[j], cc.w)));
            float ed = fmaf(cd.x, qx[j], fmaf(cd.y, qy[j], fmaf(cd.z, qz[j], cd.w)));
            mloc = (ea == tgt) ? (tb + 3) : mloc;
            mloc = (eb == tgt) ? (tb + 2) : mloc;
            mloc = (ec == tgt) ? (tb + 1) : mloc;
            mloc = (ed == tgt) ? (tb + 0) : mloc;
        }
        int gi = n0 + (gb[j] << 4) + ((mloc < G) ? mloc : 0);
        bi[j] = (gi > NN - 1) ? (NN - 1) : gi;   // pad corner clamp
    }

    // rare fallback: unfiltered min is a too-close candidate -> rescan this
    // segment with the full filter (if the min passes, all candidates do).
#pragma unroll
    for (int j = 0; j < QT; j++) {
        float tmin = MIN_T2 - qc2[j];
        if (bd[j] < tmin) {
            float fb = __builtin_inff(); int fi = 0;
            for (int i = 0; i < segn; i++) {
                float4 c = lds[(i >> 4) * GSTRIDE + (i & (G - 1))];
                float e = fmaf(c.x, qx[j], fmaf(c.y, qy[j], fmaf(c.z, qz[j], c.w)));
                bool ok = (e >= tmin) && (e < fb);
                fb = ok ? e : fb;
                fi = ok ? (n0 + i) : fi;
            }
            bd[j] = fb; bi[j] = fi;
        }
    }

    // coalesced partial store: d2 = e + qc2 >= MIN_T2 > 0 (or +inf), so
    // float bits order correctly as unsigned; low 32 bits = idx tiebreak.
#pragma unroll
    for (int j = 0; j < QT; j++) {
        int q = b * MM + m0 + j * TPB;
        float d2 = bd[j] + qc2[j];
        unsigned long long key =
            ((unsigned long long)__float_as_uint(d2) << 32) | (unsigned)bi[j];
        partials[(size_t)seg * NQ + q] = key;
    }
}

// Kernel 2: per-query u64-min over NSEG=64 segment partials, fully unrolled
// with 8 independent accumulators so all loads are in flight. Then gather
// target, contribution, block-reduce. Plain per-block stores (NO device
// atomics: R7 showed 256 same-line RMWs across XCDs cost more than the
// launch they save).
__global__ __launch_bounds__(128) void finalize_kernel(
    const unsigned long long* __restrict__ partials,
    const int* __restrict__ smpl_idx, const float* __restrict__ sdf,
    const int* __restrict__ cloth_idx, const float* __restrict__ sdf_thresh,
    const float* __restrict__ dist_thresh,
    float* __restrict__ bsum, int* __restrict__ bmatch)
{
    int q = blockIdx.x * 128 + threadIdx.x;   // 256 blocks x 128 = NQ
    int b = q >> 13;
    unsigned long long mm[8];
#pragma unroll
    for (int k = 0; k < 8; k++) mm[k] = ~0ULL;
#pragma unroll
    for (int s = 0; s < NSEG; s += 8) {
#pragma unroll
        for (int k = 0; k < 8; k++)
            mm[k] = u64min(mm[k], partials[(size_t)(s + k) * NQ + q]);
    }
    unsigned long long key =
        u64min(u64min(u64min(mm[0], mm[1]), u64min(mm[2], mm[3])),
               u64min(u64min(mm[4], mm[5]), u64min(mm[6], mm[7])));

    float d2  = __uint_as_float((unsigned)(key >> 32));
    int   idx = (int)(unsigned)(key & 0xFFFFFFFFu);
    int target = smpl_idx[b * NN + idx];
    int ci0 = cloth_idx[0], ci1 = cloth_idx[1];
    bool match = (target == ci0) || (target == ci1);
    bool near_ = sqrtf(d2) < dist_thresh[0];     // inf -> false
    float s = sdf[q];
    float contrib = near_ ? (match ? fabsf(s) : fabsf(s - sdf_thresh[0])) : 0.0f;
    int mt = match ? 1 : 0;

    for (int off = 32; off > 0; off >>= 1) {
        contrib += __shfl_down(contrib, off, 64);
        mt      |= __shfl_down(mt, off, 64);
    }
    __shared__ float wsum[2];
    __shared__ int   wmat[2];
    int wave = threadIdx.x >> 6;
    if ((threadIdx.x & 63) == 0) { wsum[wave] = contrib; wmat[wave] = mt; }
    __syncthreads();
    if (threadIdx.x == 0) {
        bsum[blockIdx.x]   = wsum[0] + wsum[1];
        bmatch[blockIdx.x] = wmat[0] | wmat[1];
    }
}

// Kernel 3: 256 block-partials -> 4 batch losses (64 partials per batch,
// one wave per batch).
__global__ __launch_bounds__(256) void reduce_kernel(
    const float* __restrict__ bs, const int* __restrict__ bm,
    float* __restrict__ out)
{
    int t = threadIdx.x;          // batch = t>>6
    float s = bs[t];
    int   m = bm[t];
    for (int off = 32; off > 0; off >>= 1) {
        s += __shfl_down(s, off, 64);
        m |= __shfl_down(m, off, 64);
    }
    if ((t & 63) == 0)
        out[t >> 6] = s * (1.0f / (float)MM) * (m ? 1.0f : 0.0f);
}

extern "C" void kernel_launch(void* const* d_in, const int* in_sizes, int n_in,
                              void* d_out, int out_size, void* d_ws, size_t ws_size,
                              hipStream_t stream)
{
    const float* sdf         = (const float*)d_in[0];
    const float* cloth       = (const float*)d_in[1];
    const int*   smpl_idx    = (const int*)d_in[2];
    const int*   valid       = (const int*)d_in[3];
    const int*   cloth_idx   = (const int*)d_in[4];
    const float* sdf_thresh  = (const float*)d_in[5];
    const float* dist_thresh = (const float*)d_in[6];
    const float* vt          = (const float*)d_in[7];

    char* ws = (char*)d_ws;
    unsigned long long* partials = (unsigned long long*)ws;
    float* bsum   = (float*)(ws + OFF_BSUM);
    int*   bmatch = (int*)(ws + OFF_BMATCH);

    nn_kernel<<<BB * CHUNKS * NSEG, TPB, 0, stream>>>(cloth, vt, valid, partials);
    finalize_kernel<<<NQ / 128, 128, 0, stream>>>(
        partials, smpl_idx, sdf, cloth_idx, sdf_thresh, dist_thresh,
        bsum, bmatch);
    reduce_kernel<<<1, 256, 0, stream>>>(bsum, bmatch, (float*)d_out);
}

// Round 9
// 103.405 us; speedup vs baseline: 1.2257x; 1.0495x over previous
//
#include <hip/hip_runtime.h>
#include <cstdint>
#include <cstddef>

// Problem constants (match reference file)
#define BB 4
#define MM 8192
#define NN 6890
#define NSEG 64
#define SEGN 108          // ceil(6890/64); last segment has 86
#define G 16              // tournament group size
#define GMAX 7            // max groups per segment
#define GSTRIDE 17        // group stride in float4 slots (bank-spread pad)
#define CHUNKS 8          // MM / MQ
#define MQ 1024           // queries per nn block (TPB * QT)
#define QT 4              // queries per thread
#define TPB 256
#define NQ (BB * MM)      // 32768 queries

static constexpr float MIN_T2 = 0.005f * 0.005f;   // MIN_DIST_THRESH^2

// ws layout (bytes):
//   [0, 16777216)            u64 partials[NSEG][NQ]  (d2_bits<<32 | idx)
//   [16777216, +1024)        float bsum[256]
//   [16778240, +1024)        int   bmatch[256]
#define OFF_BSUM   16777216
#define OFF_BMATCH (16777216 + 1024)

static __device__ __forceinline__ unsigned long long u64min(
    unsigned long long a, unsigned long long b) { return a < b ? a : b; }

// Kernel 1: per-(batch, m-chunk, n-segment) NN, group tournament.
// R8 post-mortem: batch-4 recovery staging neutral -> recovery latency was
// NOT the stall. Revised model: R4's VALUBusy 58.6% is the gfx94x derived
// formula (4cy/inst, SIMD-16); gfx950 is SIMD-32 (2cy) -> real VALU busy
// ~29% x 44us = 12.9us, matching the instruction model exactly. nn (~37us)
// is ~2/3 STALLED, and it isn't LDS (conflicts 0), VMEM BW (FETCH 1.9MB),
// or spill. Remaining suspect: TLP/balance -- 512 blocks = 2 blocks/CU
// (+-50% imbalance granularity) at only 4 waves/SIMD.
// R9 single-variable test: grid 512x512thr -> 2048x256thr (CHUNKS 8, QT 4).
// 8 blocks/CU x 4 waves = 8 waves/SIMD (2x TLP, +-12.5% balance) at
// IDENTICAL per-SIMD issue work and identical arithmetic/tiebreaks.
// QT=4 halves per-query state so VGPR ~50 <= 64 (the 8-waves/SIMD cap);
// if allocator exceeds 64 we degrade to 6 waves/SIMD, still > today's 4.
__global__ __launch_bounds__(TPB) void nn_kernel(
    const float* __restrict__ cloth, const float* __restrict__ vt,
    const int* __restrict__ valid, unsigned long long* __restrict__ partials)
{
    __shared__ float4 lds[GMAX * GSTRIDE];   // 119 float4 = 1904 B
    int bid   = blockIdx.x;            // 2048 blocks = 8/CU
    int seg   = bid & (NSEG - 1);
    int chunk = (bid >> 6) & (CHUNKS - 1);
    int b     = bid >> 9;
    int n0    = seg * SEGN;
    int segn  = (NN - n0 < SEGN) ? (NN - n0) : SEGN;
    int ngroups = (segn + G - 1) / G;
    int npad    = ngroups * G;

    // fused candidate prep: (-2x,-2y,-2z, s2 or +inf if invalid); pads inert
    if (threadIdx.x < npad) {
        float4 v = make_float4(0.0f, 0.0f, 0.0f, __builtin_inff());
        if (threadIdx.x < segn) {
            int n = n0 + threadIdx.x;
            const float* p = vt + ((size_t)b * NN + n) * 3;
            float x = p[0], y = p[1], z = p[2];
            float s2 = x * x + y * y + z * z;
            if (valid[b * NN + n] <= 0) s2 = __builtin_inff();
            v = make_float4(-2.0f * x, -2.0f * y, -2.0f * z, s2);
        }
        int slot = (threadIdx.x >> 4) * GSTRIDE + (threadIdx.x & (G - 1));
        lds[slot] = v;
    }

    float qx[QT], qy[QT], qz[QT], qc2[QT], bd[QT];
    int gb[QT];
    int m0 = chunk * MQ + threadIdx.x;
#pragma unroll
    for (int j = 0; j < QT; j++) {
        int m = m0 + j * TPB;
        const float* p = cloth + ((size_t)b * MM + m) * 3;
        float x = p[0], y = p[1], z = p[2];
        qx[j] = x; qy[j] = y; qz[j] = z;
        qc2[j] = x * x + y * y + z * z;
        bd[j] = __builtin_inff();
        gb[j] = 0;
    }
    __syncthreads();

    // Hot loop: UNFILTERED value-min in shifted space e = s2 - 2 c.s,
    // group tournament, candidates in pairs -> min3 fold.
    for (int g = 0; g < ngroups; g++) {
        int base = g * GSTRIDE;
        float gm[QT];
#pragma unroll
        for (int j = 0; j < QT; j++) gm[j] = __builtin_inff();
#pragma unroll
        for (int t = 0; t < G; t += 2) {
            float4 c0 = lds[base + t];
            float4 c1 = lds[base + t + 1];
#pragma unroll
            for (int j = 0; j < QT; j++) {
                float e0 = fmaf(c0.x, qx[j],
                           fmaf(c0.y, qy[j], fmaf(c0.z, qz[j], c0.w)));
                float e1 = fmaf(c1.x, qx[j],
                           fmaf(c1.y, qy[j], fmaf(c1.z, qz[j], c1.w)));
                gm[j] = fminf(fminf(e0, e1), gm[j]);
            }
        }
#pragma unroll
        for (int j = 0; j < QT; j++) {
            bool ok = gm[j] < bd[j];
            bd[j] = ok ? gm[j] : bd[j];
            gb[j] = ok ? g : gb[j];
        }
    }

    // index recovery: equality rescan of the winning group, batches of 4
    // candidates staged in NAMED float4s (no arrays -> no scratch).
    // Batches high->low, within-batch high->low: lowest matching t
    // assigned last -> lowest-index tiebreak (verified absmax 0.0 R7/R8).
    int bi[QT];
#pragma unroll
    for (int j = 0; j < QT; j++) {
        int base = gb[j] * GSTRIDE;
        float tgt = bd[j];
        int mloc = G;                    // G = not found (unreachable)
#pragma unroll
        for (int tb = G - 4; tb >= 0; tb -= 4) {
            float4 ca = lds[base + tb + 3];
            float4 cb = lds[base + tb + 2];
            float4 cc = lds[base + tb + 1];
            float4 cd = lds[base + tb + 0];
            float ea = fmaf(ca.x, qx[j], fmaf(ca.y, qy[j], fmaf(ca.z, qz[j], ca.w)));
            float eb = fmaf(cb.x, qx[j], fmaf(cb.y, qy[j], fmaf(cb.z, qz[j], cb.w)));
            float ec = fmaf(cc.x, qx[j], fmaf(cc.y, qy[j], fmaf(cc.z, qz[j], cc.w)));
            float ed = fmaf(cd.x, qx[j], fmaf(cd.y, qy[j], fmaf(cd.z, qz[j], cd.w)));
            mloc = (ea == tgt) ? (tb + 3) : mloc;
            mloc = (eb == tgt) ? (tb + 2) : mloc;
            mloc = (ec == tgt) ? (tb + 1) : mloc;
            mloc = (ed == tgt) ? (tb + 0) : mloc;
        }
        int gi = n0 + (gb[j] << 4) + ((mloc < G) ? mloc : 0);
        bi[j] = (gi > NN - 1) ? (NN - 1) : gi;   // pad corner clamp
    }

    // rare fallback: unfiltered min is a too-close candidate -> rescan this
    // segment with the full filter (if the min passes, all candidates do).
#pragma unroll
    for (int j = 0; j < QT; j++) {
        float tmin = MIN_T2 - qc2[j];
        if (bd[j] < tmin) {
            float fb = __builtin_inff(); int fi = 0;
            for (int i = 0; i < segn; i++) {
                float4 c = lds[(i >> 4) * GSTRIDE + (i & (G - 1))];
                float e = fmaf(c.x, qx[j], fmaf(c.y, qy[j], fmaf(c.z, qz[j], c.w)));
                bool ok = (e >= tmin) && (e < fb);
                fb = ok ? e : fb;
                fi = ok ? (n0 + i) : fi;
            }
            bd[j] = fb; bi[j] = fi;
        }
    }

    // coalesced partial store: d2 = e + qc2 >= MIN_T2 > 0 (or +inf), so
    // float bits order correctly as unsigned; low 32 bits = idx tiebreak.
#pragma unroll
    for (int j = 0; j < QT; j++) {
        int q = b * MM + m0 + j * TPB;
        float d2 = bd[j] + qc2[j];
        unsigned long long key =
            ((unsigned long long)__float_as_uint(d2) << 32) | (unsigned)bi[j];
        partials[(size_t)seg * NQ + q] = key;
    }
}

// Kernel 2: per-query u64-min over NSEG=64 segment partials, fully unrolled
// with 8 independent accumulators so all loads are in flight. Then gather
// target, contribution, block-reduce. Plain per-block stores (NO device
// atomics: R7 showed 256 same-line RMWs across XCDs cost more than the
// launch they save).
__global__ __launch_bounds__(128) void finalize_kernel(
    const unsigned long long* __restrict__ partials,
    const int* __restrict__ smpl_idx, const float* __restrict__ sdf,
    const int* __restrict__ cloth_idx, const float* __restrict__ sdf_thresh,
    const float* __restrict__ dist_thresh,
    float* __restrict__ bsum, int* __restrict__ bmatch)
{
    int q = blockIdx.x * 128 + threadIdx.x;   // 256 blocks x 128 = NQ
    int b = q >> 13;
    unsigned long long mm[8];
#pragma unroll
    for (int k = 0; k < 8; k++) mm[k] = ~0ULL;
#pragma unroll
    for (int s = 0; s < NSEG; s += 8) {
#pragma unroll
        for (int k = 0; k < 8; k++)
            mm[k] = u64min(mm[k], partials[(size_t)(s + k) * NQ + q]);
    }
    unsigned long long key =
        u64min(u64min(u64min(mm[0], mm[1]), u64min(mm[2], mm[3])),
               u64min(u64min(mm[4], mm[5]), u64min(mm[6], mm[7])));

    float d2  = __uint_as_float((unsigned)(key >> 32));
    int   idx = (int)(unsigned)(key & 0xFFFFFFFFu);
    int target = smpl_idx[b * NN + idx];
    int ci0 = cloth_idx[0], ci1 = cloth_idx[1];
    bool match = (target == ci0) || (target == ci1);
    bool near_ = sqrtf(d2) < dist_thresh[0];     // inf -> false
    float s = sdf[q];
    float contrib = near_ ? (match ? fabsf(s) : fabsf(s - sdf_thresh[0])) : 0.0f;
    int mt = match ? 1 : 0;

    for (int off = 32; off > 0; off >>= 1) {
        contrib += __shfl_down(contrib, off, 64);
        mt      |= __shfl_down(mt, off, 64);
    }
    __shared__ float wsum[2];
    __shared__ int   wmat[2];
    int wave = threadIdx.x >> 6;
    if ((threadIdx.x & 63) == 0) { wsum[wave] = contrib; wmat[wave] = mt; }
    __syncthreads();
    if (threadIdx.x == 0) {
        bsum[blockIdx.x]   = wsum[0] + wsum[1];
        bmatch[blockIdx.x] = wmat[0] | wmat[1];
    }
}

// Kernel 3: 256 block-partials -> 4 batch losses (64 partials per batch,
// one wave per batch).
__global__ __launch_bounds__(256) void reduce_kernel(
    const float* __restrict__ bs, const int* __restrict__ bm,
    float* __restrict__ out)
{
    int t = threadIdx.x;          // batch = t>>6
    float s = bs[t];
    int   m = bm[t];
    for (int off = 32; off > 0; off >>= 1) {
        s += __shfl_down(s, off, 64);
        m |= __shfl_down(m, off, 64);
    }
    if ((t & 63) == 0)
        out[t >> 6] = s * (1.0f / (float)MM) * (m ? 1.0f : 0.0f);
}

extern "C" void kernel_launch(void* const* d_in, const int* in_sizes, int n_in,
                              void* d_out, int out_size, void* d_ws, size_t ws_size,
                              hipStream_t stream)
{
    const float* sdf         = (const float*)d_in[0];
    const float* cloth       = (const float*)d_in[1];
    const int*   smpl_idx    = (const int*)d_in[2];
    const int*   valid       = (const int*)d_in[3];
    const int*   cloth_idx   = (const int*)d_in[4];
    const float* sdf_thresh  = (const float*)d_in[5];
    const float* dist_thresh = (const float*)d_in[6];
    const float* vt          = (const float*)d_in[7];

    char* ws = (char*)d_ws;
    unsigned long long* partials = (unsigned long long*)ws;
    float* bsum   = (float*)(ws + OFF_BSUM);
    int*   bmatch = (int*)(ws + OFF_BMATCH);

    nn_kernel<<<BB * CHUNKS * NSEG, TPB, 0, stream>>>(cloth, vt, valid, partials);
    finalize_kernel<<<NQ / 128, 128, 0, stream>>>(
        partials, smpl_idx, sdf, cloth_idx, sdf_thresh, dist_thresh,
        bsum, bmatch);
    reduce_kernel<<<1, 256, 0, stream>>>(bsum, bmatch, (float*)d_out);
}